// Round 15
// baseline (380.553 us; speedup 1.0000x reference)
//
#include <hip/hip_runtime.h>
#include <hip/hip_bf16.h>
#include <stdint.h>

// QLSTM: T=256, B=2048, DIN=128, NQ=16, 4 gates. fp32 inputs, fp32 outputs.
// R19: R18 (best, 368.8us) + staggered chains with gex-in-dot latency hiding.
//   - Remaining wall: ~1040cy/step-pair vs ~300cy issue; largest unhidden
//     latency = 8 ds_bpermute/step-pair consumed immediately (60-100cy LDS
//     round-trip, 1 wave/SIMD = no TLP cover). R12's stagger failed because
//     the exchange stayed atomic inside the tail. Fix: chain B runs half a
//     step behind A; each chain's dot asm block STARTS with the OTHER
//     chain's 4 ds_bpermute and ENDS with s_waitcnt lgkmcnt(0) -> the dot's
//     ~40cy of pinned VALU issue covers the exchange latency. Fully in-asm,
//     immune to scheduler reordering (rule #18 trap avoided).
//   - Per-chain arithmetic identical to R18 (same ops/association; exchange
//     is exact data movement) -> absmax must stay exactly 0.00390625.
//   - PRODUCE keeps R18's HW v_cvt_pk_bf16_f32 split. One barrier total.

#define T_STEPS 256
#define BATCH   2048
#define DIN     128
#define NQ      16
#define DTOT    144
#define NTILE   32          // 32 tiles of 8 timesteps
#define ZROW    66          // padded z row (floats)

typedef __attribute__((ext_vector_type(8))) short bf16x8;
typedef __attribute__((ext_vector_type(4))) float f32x4;
typedef __attribute__((ext_vector_type(4))) unsigned int u32x4;

__device__ __forceinline__ float bf2f(unsigned short u) {
    union { unsigned int i; float f; } v; v.i = ((unsigned int)u) << 16; return v.f;
}
__device__ __forceinline__ float ldval(const float* p) { return *p; }
__device__ __forceinline__ float ldval(const unsigned short* p) { return bf2f(*p); }

// HW packed f32->bf16 (RNE).
__device__ __forceinline__ unsigned int cvt_pk_bf16(float a, float b) {
    unsigned int r;
    asm("v_cvt_pk_bf16_f32 %0, %1, %2" : "=v"(r) : "v"(a), "v"(b));
    return r;
}
struct bfpair { unsigned int hw, lw; };
__device__ __forceinline__ bfpair split2(float x0, float x1) {
    bfpair r;
    r.hw = cvt_pk_bf16(x0, x1);
    float r0 = __builtin_bit_cast(float, r.hw << 16);
    float r1 = __builtin_bit_cast(float, r.hw & 0xffff0000u);
    r.lw = cvt_pk_bf16(x0 - r0, x1 - r1);
    return r;
}

// ---------------- per-wave dtype detector (bf16=1, fp32=0), wave-uniform ----------------
__device__ __forceinline__ int detect_bf16(const unsigned int* __restrict__ xw, int lane) {
    int cnt = 0;
#pragma unroll
    for (int i = 0; i < 4; ++i) {
        unsigned int w = xw[lane + i * 64];
        unsigned int e = (w >> 7) & 0xFFu;
        cnt += (e >= 100u && e <= 140u) ? 1 : 0;
    }
#pragma unroll
    for (int d = 32; d > 0; d >>= 1) cnt += __shfl_down(cnt, d, 64);
    int tot = __shfl(cnt, 0, 64);
    return (tot >= 140) ? 1 : 0;
}

// ---------------- DPP helpers (schedulable intrinsics) ----------------
template <int CTRL>
__device__ __forceinline__ float dpp_sh(float v) {   // shift w/ multiplicative identity
    int r = __builtin_amdgcn_update_dpp(__builtin_bit_cast(int, 1.0f),
                                        __builtin_bit_cast(int, v),
                                        CTRL, 0xF, 0xF, false);
    return __builtin_bit_cast(float, r);
}

// cos + inclusive row-prefix product (intrinsics -> schedulable around asm)
template <int BASE>
__device__ __forceinline__ float cosprefix(float z) {
    float cz = __cosf(z);
    cz *= dpp_sh<BASE + 1>(cz);
    cz *= dpp_sh<BASE + 2>(cz);
    cz *= dpp_sh<BASE + 4>(cz);
    cz *= dpp_sh<BASE + 8>(cz);
    return cz;
}
__device__ __forceinline__ float nonlin(float cz, float kexp, float ksc, float koff) {
    float e = __builtin_amdgcn_exp2f(cz * kexp);
    float rr = __builtin_amdgcn_rcpf(1.f + e);
    return fmaf(ksc, rr, koff);
}

// ---------------- dot asm: 17-inst fused rotate-dot, prologue variant --------
__device__ __forceinline__ float dot_plain(float h, float cur, const float (&Wp)[16]) {
    float a0 = cur, a1, a2, a3;
    asm volatile(
        "s_nop 1\n\t"
        "v_fmac_f32 %0, %4, %5\n\t"
        "v_mul_f32_dpp %1, %4, %6 row_ror:4 row_mask:0xf bank_mask:0xf\n\t"
        "v_mul_f32_dpp %2, %4, %7 row_ror:8 row_mask:0xf bank_mask:0xf\n\t"
        "v_mul_f32_dpp %3, %4, %8 row_ror:12 row_mask:0xf bank_mask:0xf\n\t"
        "v_fmac_f32_dpp %0, %4, %9 row_ror:1 row_mask:0xf bank_mask:0xf\n\t"
        "v_fmac_f32_dpp %1, %4, %10 row_ror:5 row_mask:0xf bank_mask:0xf\n\t"
        "v_fmac_f32_dpp %2, %4, %11 row_ror:9 row_mask:0xf bank_mask:0xf\n\t"
        "v_fmac_f32_dpp %3, %4, %12 row_ror:13 row_mask:0xf bank_mask:0xf\n\t"
        "v_fmac_f32_dpp %0, %4, %13 row_ror:2 row_mask:0xf bank_mask:0xf\n\t"
        "v_fmac_f32_dpp %1, %4, %14 row_ror:6 row_mask:0xf bank_mask:0xf\n\t"
        "v_fmac_f32_dpp %2, %4, %15 row_ror:10 row_mask:0xf bank_mask:0xf\n\t"
        "v_fmac_f32_dpp %3, %4, %16 row_ror:14 row_mask:0xf bank_mask:0xf\n\t"
        "v_fmac_f32_dpp %0, %4, %17 row_ror:3 row_mask:0xf bank_mask:0xf\n\t"
        "v_fmac_f32_dpp %1, %4, %18 row_ror:7 row_mask:0xf bank_mask:0xf\n\t"
        "v_fmac_f32_dpp %2, %4, %19 row_ror:11 row_mask:0xf bank_mask:0xf\n\t"
        "v_fmac_f32_dpp %3, %4, %20 row_ror:15 row_mask:0xf bank_mask:0xf"
        : "+v"(a0), "=&v"(a1), "=&v"(a2), "=&v"(a3)
        : "v"(h), "v"(Wp[0]), "v"(Wp[4]), "v"(Wp[8]), "v"(Wp[12]),
          "v"(Wp[1]), "v"(Wp[5]), "v"(Wp[9]), "v"(Wp[13]),
          "v"(Wp[2]), "v"(Wp[6]), "v"(Wp[10]), "v"(Wp[14]),
          "v"(Wp[3]), "v"(Wp[7]), "v"(Wp[11]), "v"(Wp[15]));
    return (a0 + a1) + (a2 + a3);
}

// ---------------- dot asm carrying the OTHER chain's gate exchange ----------
// Issues 4 ds_bpermute (other chain's s), runs the 17-inst dot (covers the
// LDS latency), drains lgkmcnt at the end. Exchange is exact data movement.
__device__ __forceinline__ float dot_gex(float h, float cur, const float (&Wp)[16],
                                         float s_o, int a_f, int a_i, int a_g, int a_o,
                                         float& fv, float& iv, float& gv, float& ov)
{
    float a0 = cur, a1, a2, a3;
    asm volatile(
        "ds_bpermute_b32 %1, %10, %9\n\t"
        "ds_bpermute_b32 %2, %11, %9\n\t"
        "ds_bpermute_b32 %3, %12, %9\n\t"
        "ds_bpermute_b32 %4, %13, %9\n\t"
        "v_fmac_f32 %0, %8, %14\n\t"
        "v_mul_f32_dpp %5, %8, %15 row_ror:4 row_mask:0xf bank_mask:0xf\n\t"
        "v_mul_f32_dpp %6, %8, %16 row_ror:8 row_mask:0xf bank_mask:0xf\n\t"
        "v_mul_f32_dpp %7, %8, %17 row_ror:12 row_mask:0xf bank_mask:0xf\n\t"
        "v_fmac_f32_dpp %0, %8, %18 row_ror:1 row_mask:0xf bank_mask:0xf\n\t"
        "v_fmac_f32_dpp %5, %8, %19 row_ror:5 row_mask:0xf bank_mask:0xf\n\t"
        "v_fmac_f32_dpp %6, %8, %20 row_ror:9 row_mask:0xf bank_mask:0xf\n\t"
        "v_fmac_f32_dpp %7, %8, %21 row_ror:13 row_mask:0xf bank_mask:0xf\n\t"
        "v_fmac_f32_dpp %0, %8, %22 row_ror:2 row_mask:0xf bank_mask:0xf\n\t"
        "v_fmac_f32_dpp %5, %8, %23 row_ror:6 row_mask:0xf bank_mask:0xf\n\t"
        "v_fmac_f32_dpp %6, %8, %24 row_ror:10 row_mask:0xf bank_mask:0xf\n\t"
        "v_fmac_f32_dpp %7, %8, %25 row_ror:14 row_mask:0xf bank_mask:0xf\n\t"
        "v_fmac_f32_dpp %0, %8, %26 row_ror:3 row_mask:0xf bank_mask:0xf\n\t"
        "v_fmac_f32_dpp %5, %8, %27 row_ror:7 row_mask:0xf bank_mask:0xf\n\t"
        "v_fmac_f32_dpp %6, %8, %28 row_ror:11 row_mask:0xf bank_mask:0xf\n\t"
        "v_fmac_f32_dpp %7, %8, %29 row_ror:15 row_mask:0xf bank_mask:0xf\n\t"
        "s_waitcnt lgkmcnt(0)"
        : "+v"(a0), "=&v"(fv), "=&v"(iv), "=&v"(gv), "=&v"(ov),
          "=&v"(a1), "=&v"(a2), "=&v"(a3)
        : "v"(h), "v"(s_o), "v"(a_f), "v"(a_i), "v"(a_g), "v"(a_o),
          "v"(Wp[0]), "v"(Wp[4]), "v"(Wp[8]), "v"(Wp[12]),
          "v"(Wp[1]), "v"(Wp[5]), "v"(Wp[9]), "v"(Wp[13]),
          "v"(Wp[2]), "v"(Wp[6]), "v"(Wp[10]), "v"(Wp[14]),
          "v"(Wp[3]), "v"(Wp[7]), "v"(Wp[11]), "v"(Wp[15]));
    return (a0 + a1) + (a2 + a3);
}

// standalone exchange (epilogue only)
__device__ __forceinline__ void gex(float s,
                                    int a_f, int a_i, int a_g, int a_o,
                                    float& fv, float& iv, float& gv, float& ov)
{
    int si = __builtin_bit_cast(int, s);
    fv = __builtin_bit_cast(float, __builtin_amdgcn_ds_bpermute(a_f, si));
    iv = __builtin_bit_cast(float, __builtin_amdgcn_ds_bpermute(a_i, si));
    gv = __builtin_bit_cast(float, __builtin_amdgcn_ds_bpermute(a_g, si));
    ov = __builtin_bit_cast(float, __builtin_amdgcn_ds_bpermute(a_o, si));
}

// ---------------- fused per-wave main (2 staggered chains / wave) ----------------
template <int BASE, typename InT>
__device__ __forceinline__ void fused_main(
    const InT* __restrict__ x, const InT* __restrict__ W,
    const InT* __restrict__ bv, const InT* __restrict__ th,
    float* __restrict__ out, int bA, int w, int lane,
    const float (&Wp)[16], float (*zt)[ZROW],
    bf16x8 (*wfh)[64], bf16x8 (*wfl)[64])
{
    const int m = lane & 15, quad = lane >> 4;
    const int g = quad, n = m;
    const int bB = bA + 1;
    const float kexp = (g == 2) ? -2.885390082f : -1.442695041f;
    const float ksc  = (g == 2) ? 2.f : 1.f;
    const float koff = (g == 2) ? -1.f : 0.f;
    const int a_f = n << 2, a_i = (16 + n) << 2, a_g = (32 + n) << 2, a_o = (48 + n) << 2;

    // ---- cooperative W-fragment build: wave w handles k-tile kt = w ----
    if constexpr (sizeof(InT) == 2) {
#pragma unroll
        for (int nb = 0; nb < 4; ++nb)
            wfh[w * 4 + nb][lane] = *(const bf16x8*)((const unsigned short*)W +
                                    (size_t)(nb * 16 + m) * DTOT + w * 32 + quad * 8);
    } else {
#pragma unroll
        for (int nb = 0; nb < 4; ++nb) {
            const float* p = (const float*)W + (size_t)(nb * 16 + m) * DTOT + w * 32 + quad * 8;
            u32x4 hw_, lw_;
#pragma unroll
            for (int q = 0; q < 4; ++q) {
                bfpair pr = split2(p[2 * q], p[2 * q + 1]);
                hw_[q] = pr.hw;
                lw_[q] = pr.lw;
            }
            wfh[w * 4 + nb][lane] = __builtin_bit_cast(bf16x8, hw_);
            wfl[w * 4 + nb][lane] = __builtin_bit_cast(bf16x8, lw_);
        }
    }
    const float bias = ldval(bv + lane) + ldval(th + lane);
    __syncthreads();            // the ONLY barrier; wf* read-only afterwards

    // A-row m -> x row (t = tl*8 + (m&7), batch = bA + (m>>3))
    const InT* xbase = x + ((size_t)(m & 7) * BATCH + (size_t)(bA + (m >> 3))) * DIN + quad * 8;

    f32x4 rx[8]; bf16x8 rbx[4];
    auto LOAD = [&](int tl) {
        const InT* p = xbase + (size_t)tl * ((size_t)8 * BATCH * DIN);
#pragma unroll
        for (int kt = 0; kt < 4; ++kt) {
            if constexpr (sizeof(InT) == 2) {
                rbx[kt] = *(const bf16x8*)(p + kt * 32);
            } else {
                rx[2 * kt]     = *(const f32x4*)((const float*)p + kt * 32);
                rx[2 * kt + 1] = *(const f32x4*)((const float*)p + kt * 32 + 4);
            }
        }
    };
    auto PRODUCE = [&]() {
        f32x4 acc[4] = {};
#pragma unroll
        for (int kt = 0; kt < 4; ++kt) {
            if constexpr (sizeof(InT) == 2) {
#pragma unroll
                for (int nb = 0; nb < 4; ++nb)
                    acc[nb] = __builtin_amdgcn_mfma_f32_16x16x32_bf16(rbx[kt], wfh[kt * 4 + nb][lane], acc[nb], 0, 0, 0);
            } else {
                u32x4 hw_, lw_;
#pragma unroll
                for (int q = 0; q < 4; ++q) {
                    float x0 = rx[2 * kt + (q >> 1)][(q & 1) * 2];
                    float x1 = rx[2 * kt + (q >> 1)][(q & 1) * 2 + 1];
                    bfpair pr = split2(x0, x1);
                    hw_[q] = pr.hw;
                    lw_[q] = pr.lw;
                }
                bf16x8 ah = __builtin_bit_cast(bf16x8, hw_);
                bf16x8 al = __builtin_bit_cast(bf16x8, lw_);
#pragma unroll
                for (int nb = 0; nb < 4; ++nb)
                    acc[nb] = __builtin_amdgcn_mfma_f32_16x16x32_bf16(ah, wfh[kt * 4 + nb][lane], acc[nb], 0, 0, 0);
#pragma unroll
                for (int nb = 0; nb < 4; ++nb)
                    acc[nb] = __builtin_amdgcn_mfma_f32_16x16x32_bf16(al, wfh[kt * 4 + nb][lane], acc[nb], 0, 0, 0);
#pragma unroll
                for (int nb = 0; nb < 4; ++nb)
                    acc[nb] = __builtin_amdgcn_mfma_f32_16x16x32_bf16(ah, wfl[kt * 4 + nb][lane], acc[nb], 0, 0, 0);
            }
        }
#pragma unroll
        for (int nb = 0; nb < 4; ++nb)
#pragma unroll
            for (int r = 0; r < 4; ++r)
                zt[quad * 4 + r][nb * 16 + m] = acc[nb][r];
    };

    float hA = 0.f, cA = 0.f, hsA = 0.f;
    float hB = 0.f, cB = 0.f, hsB = 0.f;
    float fvA, ivA, gvA, ovA, fvB = 0.f, ivB = 0.f, gvB = 0.f, ovB = 0.f;
    float zrA[8], zrB[8];

    LOAD(0);
    PRODUCE();          // zt := tile 0
    LOAD(1);
#pragma unroll
    for (int j = 0; j < 8; ++j) zrA[j] = zt[j][lane] + bias;
#pragma unroll
    for (int j = 0; j < 8; ++j) zrB[j] = zt[8 + j][lane] + bias;

    float zA = dot_plain(hA, zrA[0], Wp);   // A leads by half a step

#pragma unroll 1
    for (int tl = 0; tl < NTILE; ++tl) {
        if (tl < NTILE - 1) PRODUCE();          // zt := tile tl+1 (tile tl drained)
        if (tl < NTILE - 2) LOAD(tl + 2);
#pragma unroll
        for (int j = 0; j < 8; ++j) {
            const int t = tl * 8 + j;
            // A-NONLIN(t)
            float czA = cosprefix<BASE>(zA);
            float sA = nonlin(czA, kexp, ksc, koff);
            // B-TAIL(t-1): consume gexB issued in the previous A-DOT asm
            if (j != 0 || tl != 0) {
                cB = fmaf(fvB, cB, ivB * gvB);
                float e2 = __builtin_amdgcn_exp2f(cB * -2.885390082f);
                float tc = fmaf(2.f, __builtin_amdgcn_rcpf(1.f + e2), -1.f);
                hB = ovB * tc;
                if (((t - 1) & 3) == g) hsB = hB;
                if (((t - 1) & 3) == 3)
                    out[(size_t)(t - 4 + g) * (BATCH * NQ) + (size_t)bB * NQ + n] = hsB;
            }
            // B-DOT(t), carrying gexA (covers its LDS latency)
            float zB = dot_gex(hB, zrB[j], Wp, sA, a_f, a_i, a_g, a_o,
                               fvA, ivA, gvA, ovA);
            // B-NONLIN(t)
            float czB = cosprefix<BASE>(zB);
            float sB = nonlin(czB, kexp, ksc, koff);
            // A-TAIL(t): consume gexA
            cA = fmaf(fvA, cA, ivA * gvA);
            {
                float e2 = __builtin_amdgcn_exp2f(cA * -2.885390082f);
                float tc = fmaf(2.f, __builtin_amdgcn_rcpf(1.f + e2), -1.f);
                hA = ovA * tc;
            }
            if ((t & 3) == g) hsA = hA;
            if ((t & 3) == 3)
                out[(size_t)(t - 3 + g) * (BATCH * NQ) + (size_t)bA * NQ + n] = hsA;
            // A-DOT(t+1), carrying gexB
            if (j < 7) {
                zA = dot_gex(hA, zrA[j + 1], Wp, sB, a_f, a_i, a_g, a_o,
                             fvB, ivB, gvB, ovB);
            } else if (tl < NTILE - 1) {
                // tile boundary: drain next tile's z, then A's first dot
#pragma unroll
                for (int k = 0; k < 8; ++k) zrA[k] = zt[k][lane] + bias;
#pragma unroll
                for (int k = 0; k < 8; ++k) zrB[k] = zt[8 + k][lane] + bias;
                zA = dot_gex(hA, zrA[0], Wp, sB, a_f, a_i, a_g, a_o,
                             fvB, ivB, gvB, ovB);
            } else {
                // last step overall: standalone gexB + B-TAIL(255)
                gex(sB, a_f, a_i, a_g, a_o, fvB, ivB, gvB, ovB);
                cB = fmaf(fvB, cB, ivB * gvB);
                float e2 = __builtin_amdgcn_exp2f(cB * -2.885390082f);
                float tc = fmaf(2.f, __builtin_amdgcn_rcpf(1.f + e2), -1.f);
                hB = ovB * tc;
                if ((3) == g) hsB = hB;                      // 255&3 == 3
                out[(size_t)(252 + g) * (BATCH * NQ) + (size_t)bB * NQ + n] = hsB;
            }
        }
    }

    if (g == 0) {
        out[(size_t)T_STEPS * BATCH * NQ + (size_t)bA * NQ + n] = hA;                      // hx
        out[(size_t)T_STEPS * BATCH * NQ + (size_t)BATCH * NQ + (size_t)bA * NQ + n] = cA; // cx
        out[(size_t)T_STEPS * BATCH * NQ + (size_t)bB * NQ + n] = hB;
        out[(size_t)T_STEPS * BATCH * NQ + (size_t)BATCH * NQ + (size_t)bB * NQ + n] = cB;
    }
}

__global__ __launch_bounds__(256, 1) void qlstm_fused(
    const void* __restrict__ x_, const void* __restrict__ W_,
    const void* __restrict__ b_, const void* __restrict__ th_,
    float* __restrict__ out)
{
    __shared__ float  zw[4][16][ZROW];      // 16.5 KiB: per-wave z tiles
    __shared__ bf16x8 wfh[16][64];          // 16 KiB: W hi fragments (shared)
    __shared__ bf16x8 wfl[16][64];          // 16 KiB: W lo fragments (fp32 path)

    const int lane = threadIdx.x & 63;
    const int w    = threadIdx.x >> 6;
    const int bA   = (blockIdx.x * 4 + w) * 2;
    const int n    = lane & 15;

    const int isbf = __builtin_amdgcn_readfirstlane(detect_bf16((const unsigned int*)x_, lane));

    // runtime probe of DPP row_ror direction (wave-uniform)
    int pr  = __builtin_amdgcn_update_dpp(0, lane, 0x121, 0xF, 0xF, false);
    int p0r = __shfl(pr, 0, 64);
    const int d = (p0r == 1) ? 1 : 15;

    float Wp[16];
    if (isbf) {
        const unsigned short* W = (const unsigned short*)W_;
#pragma unroll
        for (int k = 0; k < 16; ++k)
            Wp[k] = bf2f(W[(size_t)lane * DTOT + DIN + ((n + k * d) & 15)]);
    } else {
        const float* W = (const float*)W_;
#pragma unroll
        for (int k = 0; k < 16; ++k)
            Wp[k] = W[(size_t)lane * DTOT + DIN + ((n + k * d) & 15)];
    }

    // runtime probe of DPP row_shr direction (wave-uniform) for the prefix product
    int probe = __builtin_amdgcn_update_dpp(999, lane, 0x111, 0xF, 0xF, false);
    int p2 = __shfl(probe, 2, 64);

    if (isbf) {
        if (p2 == 1) fused_main<0x110, unsigned short>((const unsigned short*)x_, (const unsigned short*)W_,
                                                       (const unsigned short*)b_, (const unsigned short*)th_,
                                                       out, bA, w, lane, Wp, zw[w], wfh, wfl);
        else         fused_main<0x100, unsigned short>((const unsigned short*)x_, (const unsigned short*)W_,
                                                       (const unsigned short*)b_, (const unsigned short*)th_,
                                                       out, bA, w, lane, Wp, zw[w], wfh, wfl);
    } else {
        if (p2 == 1) fused_main<0x110, float>((const float*)x_, (const float*)W_,
                                              (const float*)b_, (const float*)th_,
                                              out, bA, w, lane, Wp, zw[w], wfh, wfl);
        else         fused_main<0x100, float>((const float*)x_, (const float*)W_,
                                              (const float*)b_, (const float*)th_,
                                              out, bA, w, lane, Wp, zw[w], wfh, wfl);
    }
}

extern "C" void kernel_launch(void* const* d_in, const int* in_sizes, int n_in,
                              void* d_out, int out_size, void* d_ws, size_t ws_size,
                              hipStream_t stream) {
    const void* x  = d_in[0];
    const void* W  = d_in[1];
    const void* bv = d_in[2];
    const void* th = d_in[3];
    (void)d_ws; (void)ws_size;
    qlstm_fused<<<BATCH / 8, 256, 0, stream>>>(x, W, bv, th, (float*)d_out);
}

// Round 16
// 374.871 us; speedup vs baseline: 1.0152x; 1.0152x over previous
//
#include <hip/hip_runtime.h>
#include <hip/hip_bf16.h>
#include <stdint.h>

// QLSTM: T=256, B=2048, DIN=128, NQ=16, 4 gates. fp32 inputs, fp32 outputs.
// R20 = R18 verbatim (best measured: 368.8us). R19's stagger+gex-in-dot
// regressed (380.6) -> reverted per pre-commit. Session ledger:
//   466.7 baseline -> 441.7 (fuse, kill xz) -> 394.8 (LDS conflicts) ->
//   388.7 (DPP-fused dot) -> 385.1 (2 chains/wave) -> 378.1 (bpermute gex)
//   -> 368.8 (HW cvt_pk bf16 split).  Wins came ONLY from issued-instruction
//   reduction; all schedule/transport/occupancy restructures were null or
//   regressions. Remaining per-step blocks are at their minimal op counts.

#define T_STEPS 256
#define BATCH   2048
#define DIN     128
#define NQ      16
#define DTOT    144
#define NTILE   32          // 32 tiles of 8 timesteps
#define ZROW    66          // padded z row (floats)

typedef __attribute__((ext_vector_type(8))) short bf16x8;
typedef __attribute__((ext_vector_type(4))) float f32x4;
typedef __attribute__((ext_vector_type(4))) unsigned int u32x4;

__device__ __forceinline__ float bf2f(unsigned short u) {
    union { unsigned int i; float f; } v; v.i = ((unsigned int)u) << 16; return v.f;
}
__device__ __forceinline__ unsigned short f2bf(float f) {
    union { float f; unsigned int i; } v; v.f = f;
    unsigned int i = v.i;
    unsigned int r = i + 0x7fffu + ((i >> 16) & 1u);   // round-nearest-even
    return (unsigned short)(r >> 16);
}
__device__ __forceinline__ float ldval(const float* p) { return *p; }
__device__ __forceinline__ float ldval(const unsigned short* p) { return bf2f(*p); }

// HW packed f32->bf16 (RNE), dst.lo = cvt(a), dst.hi = cvt(b). Pure asm (no
// volatile) so the scheduler stays free.
__device__ __forceinline__ unsigned int cvt_pk_bf16(float a, float b) {
    unsigned int r;
    asm("v_cvt_pk_bf16_f32 %0, %1, %2" : "=v"(r) : "v"(a), "v"(b));
    return r;
}
struct bfpair { unsigned int hw, lw; };
// hi/lo split of two f32 into packed bf16 words: hw = hi parts, lw = lo parts.
__device__ __forceinline__ bfpair split2(float x0, float x1) {
    bfpair r;
    r.hw = cvt_pk_bf16(x0, x1);
    float r0 = __builtin_bit_cast(float, r.hw << 16);
    float r1 = __builtin_bit_cast(float, r.hw & 0xffff0000u);
    r.lw = cvt_pk_bf16(x0 - r0, x1 - r1);
    return r;
}

// ---------------- per-wave dtype detector (bf16=1, fp32=0), wave-uniform ----------------
__device__ __forceinline__ int detect_bf16(const unsigned int* __restrict__ xw, int lane) {
    int cnt = 0;
#pragma unroll
    for (int i = 0; i < 4; ++i) {
        unsigned int w = xw[lane + i * 64];
        unsigned int e = (w >> 7) & 0xFFu;
        cnt += (e >= 100u && e <= 140u) ? 1 : 0;
    }
#pragma unroll
    for (int d = 32; d > 0; d >>= 1) cnt += __shfl_down(cnt, d, 64);
    int tot = __shfl(cnt, 0, 64);
    return (tot >= 140) ? 1 : 0;
}

// ---------------- gate exchange: s(row g) -> f/i/g/o at qubit n (exact) ----------------
__device__ __forceinline__ void gex(float s,
                                    int a_f, int a_i, int a_g, int a_o,
                                    float& fv, float& iv, float& gv, float& ov)
{
    int si = __builtin_bit_cast(int, s);
    fv = __builtin_bit_cast(float, __builtin_amdgcn_ds_bpermute(a_f, si));
    iv = __builtin_bit_cast(float, __builtin_amdgcn_ds_bpermute(a_i, si));
    gv = __builtin_bit_cast(float, __builtin_amdgcn_ds_bpermute(a_g, si));
    ov = __builtin_bit_cast(float, __builtin_amdgcn_ds_bpermute(a_o, si));
}

// ---------------- one recurrence step for TWO batches ----------------
template <int BASE>
__device__ __forceinline__ void qstep2(int t, int g, int n,
                                       float curA, float curB, const float (&Wp)[16],
                                       float& hA, float& cA, float& hsA, int bA,
                                       float& hB, float& cB, float& hsB, int bB,
                                       float kexp, float ksc, float koff,
                                       int a_f, int a_i, int a_g, int a_o,
                                       float* __restrict__ out)
{
    // combined h-dot: A/B chains interleaved; accumulator reuse distance 8 inst.
    float a0A = curA, a1A, a2A, a3A;
    float a0B = curB, a1B, a2B, a3B;
    asm volatile(
        "s_nop 1\n\t"
        "v_fmac_f32 %0, %8, %10\n\t"
        "v_fmac_f32 %4, %9, %10\n\t"
        "v_mul_f32_dpp %1, %8, %11 row_ror:4 row_mask:0xf bank_mask:0xf\n\t"
        "v_mul_f32_dpp %5, %9, %11 row_ror:4 row_mask:0xf bank_mask:0xf\n\t"
        "v_mul_f32_dpp %2, %8, %12 row_ror:8 row_mask:0xf bank_mask:0xf\n\t"
        "v_mul_f32_dpp %6, %9, %12 row_ror:8 row_mask:0xf bank_mask:0xf\n\t"
        "v_mul_f32_dpp %3, %8, %13 row_ror:12 row_mask:0xf bank_mask:0xf\n\t"
        "v_mul_f32_dpp %7, %9, %13 row_ror:12 row_mask:0xf bank_mask:0xf\n\t"
        "v_fmac_f32_dpp %0, %8, %14 row_ror:1 row_mask:0xf bank_mask:0xf\n\t"
        "v_fmac_f32_dpp %4, %9, %14 row_ror:1 row_mask:0xf bank_mask:0xf\n\t"
        "v_fmac_f32_dpp %1, %8, %15 row_ror:5 row_mask:0xf bank_mask:0xf\n\t"
        "v_fmac_f32_dpp %5, %9, %15 row_ror:5 row_mask:0xf bank_mask:0xf\n\t"
        "v_fmac_f32_dpp %2, %8, %16 row_ror:9 row_mask:0xf bank_mask:0xf\n\t"
        "v_fmac_f32_dpp %6, %9, %16 row_ror:9 row_mask:0xf bank_mask:0xf\n\t"
        "v_fmac_f32_dpp %3, %8, %17 row_ror:13 row_mask:0xf bank_mask:0xf\n\t"
        "v_fmac_f32_dpp %7, %9, %17 row_ror:13 row_mask:0xf bank_mask:0xf\n\t"
        "v_fmac_f32_dpp %0, %8, %18 row_ror:2 row_mask:0xf bank_mask:0xf\n\t"
        "v_fmac_f32_dpp %4, %9, %18 row_ror:2 row_mask:0xf bank_mask:0xf\n\t"
        "v_fmac_f32_dpp %1, %8, %19 row_ror:6 row_mask:0xf bank_mask:0xf\n\t"
        "v_fmac_f32_dpp %5, %9, %19 row_ror:6 row_mask:0xf bank_mask:0xf\n\t"
        "v_fmac_f32_dpp %2, %8, %20 row_ror:10 row_mask:0xf bank_mask:0xf\n\t"
        "v_fmac_f32_dpp %6, %9, %20 row_ror:10 row_mask:0xf bank_mask:0xf\n\t"
        "v_fmac_f32_dpp %3, %8, %21 row_ror:14 row_mask:0xf bank_mask:0xf\n\t"
        "v_fmac_f32_dpp %7, %9, %21 row_ror:14 row_mask:0xf bank_mask:0xf\n\t"
        "v_fmac_f32_dpp %0, %8, %22 row_ror:3 row_mask:0xf bank_mask:0xf\n\t"
        "v_fmac_f32_dpp %4, %9, %22 row_ror:3 row_mask:0xf bank_mask:0xf\n\t"
        "v_fmac_f32_dpp %1, %8, %23 row_ror:7 row_mask:0xf bank_mask:0xf\n\t"
        "v_fmac_f32_dpp %5, %9, %23 row_ror:7 row_mask:0xf bank_mask:0xf\n\t"
        "v_fmac_f32_dpp %2, %8, %24 row_ror:11 row_mask:0xf bank_mask:0xf\n\t"
        "v_fmac_f32_dpp %6, %9, %24 row_ror:11 row_mask:0xf bank_mask:0xf\n\t"
        "v_fmac_f32_dpp %3, %8, %25 row_ror:15 row_mask:0xf bank_mask:0xf\n\t"
        "v_fmac_f32_dpp %7, %9, %25 row_ror:15 row_mask:0xf bank_mask:0xf"
        : "+v"(a0A), "=&v"(a1A), "=&v"(a2A), "=&v"(a3A),
          "+v"(a0B), "=&v"(a1B), "=&v"(a2B), "=&v"(a3B)
        : "v"(hA), "v"(hB),
          "v"(Wp[0]), "v"(Wp[4]), "v"(Wp[8]), "v"(Wp[12]),
          "v"(Wp[1]), "v"(Wp[5]), "v"(Wp[9]), "v"(Wp[13]),
          "v"(Wp[2]), "v"(Wp[6]), "v"(Wp[10]), "v"(Wp[14]),
          "v"(Wp[3]), "v"(Wp[7]), "v"(Wp[11]), "v"(Wp[15]));
    float zA = (a0A + a1A) + (a2A + a3A);
    float zB = (a0B + a1B) + (a2B + a3B);

    float czA = __cosf(zA);
    float czB = __cosf(zB);
    // combined inclusive prefix product (DPP Hillis-Steele), A/B interleaved:
    // invalid lanes keep dst (BC=0) = multiplicative identity; the other
    // chain's instruction covers each DPP hazard slot.
    if constexpr (BASE == 0x110) {
        asm volatile(
            "s_nop 1\n\t"
            "v_mul_f32_dpp %0, %0, %0 row_shr:1 row_mask:0xf bank_mask:0xf\n\t"
            "v_mul_f32_dpp %1, %1, %1 row_shr:1 row_mask:0xf bank_mask:0xf\n\t"
            "v_mul_f32_dpp %0, %0, %0 row_shr:2 row_mask:0xf bank_mask:0xf\n\t"
            "v_mul_f32_dpp %1, %1, %1 row_shr:2 row_mask:0xf bank_mask:0xf\n\t"
            "v_mul_f32_dpp %0, %0, %0 row_shr:4 row_mask:0xf bank_mask:0xf\n\t"
            "v_mul_f32_dpp %1, %1, %1 row_shr:4 row_mask:0xf bank_mask:0xf\n\t"
            "v_mul_f32_dpp %0, %0, %0 row_shr:8 row_mask:0xf bank_mask:0xf\n\t"
            "v_mul_f32_dpp %1, %1, %1 row_shr:8 row_mask:0xf bank_mask:0xf"
            : "+v"(czA), "+v"(czB));
    } else {
        asm volatile(
            "s_nop 1\n\t"
            "v_mul_f32_dpp %0, %0, %0 row_shl:1 row_mask:0xf bank_mask:0xf\n\t"
            "v_mul_f32_dpp %1, %1, %1 row_shl:1 row_mask:0xf bank_mask:0xf\n\t"
            "v_mul_f32_dpp %0, %0, %0 row_shl:2 row_mask:0xf bank_mask:0xf\n\t"
            "v_mul_f32_dpp %1, %1, %1 row_shl:2 row_mask:0xf bank_mask:0xf\n\t"
            "v_mul_f32_dpp %0, %0, %0 row_shl:4 row_mask:0xf bank_mask:0xf\n\t"
            "v_mul_f32_dpp %1, %1, %1 row_shl:4 row_mask:0xf bank_mask:0xf\n\t"
            "v_mul_f32_dpp %0, %0, %0 row_shl:8 row_mask:0xf bank_mask:0xf\n\t"
            "v_mul_f32_dpp %1, %1, %1 row_shl:8 row_mask:0xf bank_mask:0xf"
            : "+v"(czA), "+v"(czB));
    }

    // gates: s = fmaf(ksc, 1/(1+2^(cz*kexp)), koff)
    float eA = __builtin_amdgcn_exp2f(czA * kexp);
    float eB = __builtin_amdgcn_exp2f(czB * kexp);
    float rrA = __builtin_amdgcn_rcpf(1.f + eA);
    float rrB = __builtin_amdgcn_rcpf(1.f + eB);
    float sA = fmaf(ksc, rrA, koff);
    float sB = fmaf(ksc, rrB, koff);

    float fvA, ivA, gvA, ovA, fvB, ivB, gvB, ovB;
    gex(sA, a_f, a_i, a_g, a_o, fvA, ivA, gvA, ovA);
    gex(sB, a_f, a_i, a_g, a_o, fvB, ivB, gvB, ovB);

    cA = fmaf(fvA, cA, ivA * gvA);
    cB = fmaf(fvB, cB, ivB * gvB);
    // tanh(c) = 2/(1+2^(-2c*log2e)) - 1
    float e2A = __builtin_amdgcn_exp2f(cA * -2.885390082f);
    float e2B = __builtin_amdgcn_exp2f(cB * -2.885390082f);
    float tcA = fmaf(2.f, __builtin_amdgcn_rcpf(1.f + e2A), -1.f);
    float tcB = fmaf(2.f, __builtin_amdgcn_rcpf(1.f + e2B), -1.f);
    hA = ovA * tcA;
    hB = ovB * tcB;

    if ((t & 3) == g) { hsA = hA; hsB = hB; }
    if ((t & 3) == 3) {
        out[(size_t)(t - 3 + g) * (BATCH * NQ) + (size_t)bA * NQ + n] = hsA;
        out[(size_t)(t - 3 + g) * (BATCH * NQ) + (size_t)bB * NQ + n] = hsB;
    }
}

// ---------------- fused per-wave main (2 batches / wave) ----------------
// MFMA A-row m <-> (batch = bA + (m>>3), t_local = m&7); 32 tiles of 8 steps.
// wfh/wfl[kt*4+nb][lane]: W fragments in LDS, built once (one barrier).
template <int BASE, typename InT>
__device__ __forceinline__ void fused_main(
    const InT* __restrict__ x, const InT* __restrict__ W,
    const InT* __restrict__ bv, const InT* __restrict__ th,
    float* __restrict__ out, int bA, int w, int lane,
    const float (&Wp)[16], float (*zt)[ZROW],
    bf16x8 (*wfh)[64], bf16x8 (*wfl)[64])
{
    const int m = lane & 15, quad = lane >> 4;
    const int g = quad, n = m;
    const int bB = bA + 1;
    const float kexp = (g == 2) ? -2.885390082f : -1.442695041f;
    const float ksc  = (g == 2) ? 2.f : 1.f;
    const float koff = (g == 2) ? -1.f : 0.f;
    const int a_f = n << 2, a_i = (16 + n) << 2, a_g = (32 + n) << 2, a_o = (48 + n) << 2;

    // ---- cooperative W-fragment build: wave w handles k-tile kt = w ----
    if constexpr (sizeof(InT) == 2) {
#pragma unroll
        for (int nb = 0; nb < 4; ++nb)
            wfh[w * 4 + nb][lane] = *(const bf16x8*)((const unsigned short*)W +
                                    (size_t)(nb * 16 + m) * DTOT + w * 32 + quad * 8);
    } else {
#pragma unroll
        for (int nb = 0; nb < 4; ++nb) {
            const float* p = (const float*)W + (size_t)(nb * 16 + m) * DTOT + w * 32 + quad * 8;
            u32x4 hw_, lw_;
#pragma unroll
            for (int q = 0; q < 4; ++q) {
                bfpair pr = split2(p[2 * q], p[2 * q + 1]);
                hw_[q] = pr.hw;
                lw_[q] = pr.lw;
            }
            wfh[w * 4 + nb][lane] = __builtin_bit_cast(bf16x8, hw_);
            wfl[w * 4 + nb][lane] = __builtin_bit_cast(bf16x8, lw_);
        }
    }
    const float bias = ldval(bv + lane) + ldval(th + lane);
    __syncthreads();            // the ONLY barrier; wf* read-only afterwards

    // A-row m -> x row (t = tl*8 + (m&7), batch = bA + (m>>3))
    const InT* xbase = x + ((size_t)(m & 7) * BATCH + (size_t)(bA + (m >> 3))) * DIN + quad * 8;

    f32x4 rx[8]; bf16x8 rbx[4];
    auto LOAD = [&](int tl) {
        const InT* p = xbase + (size_t)tl * ((size_t)8 * BATCH * DIN);
#pragma unroll
        for (int kt = 0; kt < 4; ++kt) {
            if constexpr (sizeof(InT) == 2) {
                rbx[kt] = *(const bf16x8*)(p + kt * 32);
            } else {
                rx[2 * kt]     = *(const f32x4*)((const float*)p + kt * 32);
                rx[2 * kt + 1] = *(const f32x4*)((const float*)p + kt * 32 + 4);
            }
        }
    };
    auto PRODUCE = [&]() {
        f32x4 acc[4] = {};
#pragma unroll
        for (int kt = 0; kt < 4; ++kt) {
            if constexpr (sizeof(InT) == 2) {
#pragma unroll
                for (int nb = 0; nb < 4; ++nb)
                    acc[nb] = __builtin_amdgcn_mfma_f32_16x16x32_bf16(rbx[kt], wfh[kt * 4 + nb][lane], acc[nb], 0, 0, 0);
            } else {
                // HW bf16 hi/lo split: 6 inst per element-pair (was ~28 with
                // the software RNE bit-trick). RNE == RNE -> bit-identical.
                u32x4 hw_, lw_;
#pragma unroll
                for (int q = 0; q < 4; ++q) {
                    float x0 = rx[2 * kt + (q >> 1)][(q & 1) * 2];
                    float x1 = rx[2 * kt + (q >> 1)][(q & 1) * 2 + 1];
                    bfpair pr = split2(x0, x1);
                    hw_[q] = pr.hw;
                    lw_[q] = pr.lw;
                }
                bf16x8 ah = __builtin_bit_cast(bf16x8, hw_);
                bf16x8 al = __builtin_bit_cast(bf16x8, lw_);
#pragma unroll
                for (int nb = 0; nb < 4; ++nb)
                    acc[nb] = __builtin_amdgcn_mfma_f32_16x16x32_bf16(ah, wfh[kt * 4 + nb][lane], acc[nb], 0, 0, 0);
#pragma unroll
                for (int nb = 0; nb < 4; ++nb)
                    acc[nb] = __builtin_amdgcn_mfma_f32_16x16x32_bf16(al, wfh[kt * 4 + nb][lane], acc[nb], 0, 0, 0);
#pragma unroll
                for (int nb = 0; nb < 4; ++nb)
                    acc[nb] = __builtin_amdgcn_mfma_f32_16x16x32_bf16(ah, wfl[kt * 4 + nb][lane], acc[nb], 0, 0, 0);
            }
        }
        // z[row = quad*4+r][col = nb*16+m]; rows 0..7 = batch A t0..7, 8..15 = batch B
#pragma unroll
        for (int nb = 0; nb < 4; ++nb)
#pragma unroll
            for (int r = 0; r < 4; ++r)
                zt[quad * 4 + r][nb * 16 + m] = acc[nb][r];
    };

    float hA = 0.f, cA = 0.f, hsA = 0.f;
    float hB = 0.f, cB = 0.f, hsB = 0.f;

    LOAD(0);
    PRODUCE();
    LOAD(1);

#pragma unroll 1
    for (int tl = 0; tl < NTILE; ++tl) {
        const int t0 = tl * 8;
        float zrA[8], zrB[8];
#pragma unroll
        for (int j = 0; j < 8; ++j) zrA[j] = zt[j][lane] + bias;       // drain before overwrite
#pragma unroll
        for (int j = 0; j < 8; ++j) zrB[j] = zt[8 + j][lane] + bias;
        if (tl < NTILE - 1) PRODUCE();
        if (tl < NTILE - 2) LOAD(tl + 2);
#pragma unroll
        for (int j = 0; j < 8; ++j)
            qstep2<BASE>(t0 + j, g, n, zrA[j], zrB[j], Wp,
                         hA, cA, hsA, bA, hB, cB, hsB, bB,
                         kexp, ksc, koff, a_f, a_i, a_g, a_o, out);
    }

    if (g == 0) {
        out[(size_t)T_STEPS * BATCH * NQ + (size_t)bA * NQ + n] = hA;                      // hx
        out[(size_t)T_STEPS * BATCH * NQ + (size_t)BATCH * NQ + (size_t)bA * NQ + n] = cA; // cx
        out[(size_t)T_STEPS * BATCH * NQ + (size_t)bB * NQ + n] = hB;
        out[(size_t)T_STEPS * BATCH * NQ + (size_t)BATCH * NQ + (size_t)bB * NQ + n] = cB;
    }
}

__global__ __launch_bounds__(256, 1) void qlstm_fused(
    const void* __restrict__ x_, const void* __restrict__ W_,
    const void* __restrict__ b_, const void* __restrict__ th_,
    float* __restrict__ out)
{
    __shared__ float  zw[4][16][ZROW];      // 16.5 KiB: per-wave z tiles
    __shared__ bf16x8 wfh[16][64];          // 16 KiB: W hi fragments (shared)
    __shared__ bf16x8 wfl[16][64];          // 16 KiB: W lo fragments (fp32 path)

    const int lane = threadIdx.x & 63;
    const int w    = threadIdx.x >> 6;
    const int bA   = (blockIdx.x * 4 + w) * 2;
    const int n    = lane & 15;

    const int isbf = __builtin_amdgcn_readfirstlane(detect_bf16((const unsigned int*)x_, lane));

    // runtime probe of DPP row_ror direction (wave-uniform)
    int pr  = __builtin_amdgcn_update_dpp(0, lane, 0x121, 0xF, 0xF, false);
    int p0r = __shfl(pr, 0, 64);
    const int d = (p0r == 1) ? 1 : 15;

    float Wp[16];
    if (isbf) {
        const unsigned short* W = (const unsigned short*)W_;
#pragma unroll
        for (int k = 0; k < 16; ++k)
            Wp[k] = bf2f(W[(size_t)lane * DTOT + DIN + ((n + k * d) & 15)]);
    } else {
        const float* W = (const float*)W_;
#pragma unroll
        for (int k = 0; k < 16; ++k)
            Wp[k] = W[(size_t)lane * DTOT + DIN + ((n + k * d) & 15)];
    }

    // runtime probe of DPP row_shr direction (wave-uniform) for the prefix product
    int probe = __builtin_amdgcn_update_dpp(999, lane, 0x111, 0xF, 0xF, false);
    int p2 = __shfl(probe, 2, 64);

    if (isbf) {
        if (p2 == 1) fused_main<0x110, unsigned short>((const unsigned short*)x_, (const unsigned short*)W_,
                                                       (const unsigned short*)b_, (const unsigned short*)th_,
                                                       out, bA, w, lane, Wp, zw[w], wfh, wfl);
        else         fused_main<0x100, unsigned short>((const unsigned short*)x_, (const unsigned short*)W_,
                                                       (const unsigned short*)b_, (const unsigned short*)th_,
                                                       out, bA, w, lane, Wp, zw[w], wfh, wfl);
    } else {
        if (p2 == 1) fused_main<0x110, float>((const float*)x_, (const float*)W_,
                                              (const float*)b_, (const float*)th_,
                                              out, bA, w, lane, Wp, zw[w], wfh, wfl);
        else         fused_main<0x100, float>((const float*)x_, (const float*)W_,
                                              (const float*)b_, (const float*)th_,
                                              out, bA, w, lane, Wp, zw[w], wfh, wfl);
    }
}

extern "C" void kernel_launch(void* const* d_in, const int* in_sizes, int n_in,
                              void* d_out, int out_size, void* d_ws, size_t ws_size,
                              hipStream_t stream) {
    const void* x  = d_in[0];
    const void* W  = d_in[1];
    const void* bv = d_in[2];
    const void* th = d_in[3];
    (void)d_ws; (void)ws_size;
    qlstm_fused<<<BATCH / 8, 256, 0, stream>>>(x, W, bv, th, (float*)d_out);
}